// Round 2
// 554.063 us; speedup vs baseline: 1.0175x; 1.0175x over previous
//
#include <hip/hip_runtime.h>
#include <math.h>

// FFT-based 2D circular convolution, B=4,C=64,H=251,W=509 -> pad 256x512.
// z = u + i*k packing; register radix-8 FFTs (8 pts/thread, 2 LDS exchanges);
// all inverse transforms via conj-trick on the forward machinery.
// zt layout: [imgl][w (natural freq)][h] -- columns contiguous (2 KB).
//
// R2 = R1 (never ran: infra failure) + float4 transpose-edge vectorization:
//  - wave-private LDS phases: __syncthreads -> wave_barrier everywhere except
//    the genuinely cross-wave transpose points (kA final gather, kC initial
//    scatter + final gather). kB is 100% wave-local -> zero real barriers.
//  - phase-2->3 exchange XOR swizzle in kA/kC (was an 8-lane/bank-pair conflict).
//  - XCD pair swizzle of blockIdx in kA/kC so h0-adjacent blocks (which touch
//    the two 64B halves of each 128B zt line) land on the same XCD L2.
//  - tw8: 1 sincos + 6 cmul recurrence instead of 7 sincos.
//  - kB occupancy 4->6 blocks/CU.
//  - NEW: kA zt-store / kC zt-load as dwordx4 (pair adjacent h per lane).

#define H_IN 251
#define W_IN 509
#define NIMG 256
#define LROW 516        // 512 + 4 pad (transpose staging anti-conflict)
#define CSTR 264        // 256 + 8 pad (kB column stride)

#define WBAR() __builtin_amdgcn_wave_barrier()

__device__ __forceinline__ float2 cadd(float2 a, float2 b){ return make_float2(a.x+b.x, a.y+b.y); }
__device__ __forceinline__ float2 csub(float2 a, float2 b){ return make_float2(a.x-b.x, a.y-b.y); }
__device__ __forceinline__ float2 cmul(float2 a, float2 b){ return make_float2(a.x*b.x-a.y*b.y, a.x*b.y+a.y*b.x); }
__device__ __forceinline__ float2 mnegi(float2 a){ return make_float2(a.y, -a.x); }   // a * (-i)

// 8-pt DFT, natural in -> natural out (DIF + in-register unscramble).
__device__ __forceinline__ void dft8(float2 x[8]) {
    const float s = 0.70710678118654752f;
    float2 y0=cadd(x[0],x[4]), y4=csub(x[0],x[4]);
    float2 y1=cadd(x[1],x[5]), y5=csub(x[1],x[5]);
    float2 y2=cadd(x[2],x[6]), y6=csub(x[2],x[6]);
    float2 y3=cadd(x[3],x[7]), y7=csub(x[3],x[7]);
    y5 = cmul(y5, make_float2(s, -s));
    y6 = mnegi(y6);
    y7 = cmul(y7, make_float2(-s, -s));
    float2 z0=cadd(y0,y2), z2=csub(y0,y2);
    float2 z1=cadd(y1,y3), z3=mnegi(csub(y1,y3));
    float2 z4=cadd(y4,y6), z6=csub(y4,y6);
    float2 z5=cadd(y5,y7), z7=mnegi(csub(y5,y7));
    float2 p0=cadd(z0,z1), p1=csub(z0,z1);
    float2 p2=cadd(z2,z3), p3=csub(z2,z3);
    float2 p4=cadd(z4,z5), p5=csub(z4,z5);
    float2 p6=cadd(z6,z7), p7=csub(z6,z7);
    x[0]=p0; x[1]=p4; x[2]=p2; x[3]=p6; x[4]=p1; x[5]=p5; x[6]=p3; x[7]=p7;
}

// 4-pt DFT, natural in -> natural out.
__device__ __forceinline__ void dft4(float2 x[4]) {
    float2 a=cadd(x[0],x[2]), c=csub(x[0],x[2]);
    float2 b=cadd(x[1],x[3]), d=mnegi(csub(x[1],x[3]));
    float2 p0=cadd(a,b), p1=csub(a,b);
    float2 p2=cadd(c,d), p3=csub(c,d);
    x[0]=p0; x[1]=p2; x[2]=p1; x[3]=p3;
}

// v[q] *= e^{i*ang1*q}, q=1..7 : one sincos + power recurrence (6 cmul).
__device__ __forceinline__ void tw8(float2 v[8], float ang1) {
    float sn, cs; __sincosf(ang1, &sn, &cs);
    const float2 w1 = make_float2(cs, sn);
    const float2 w2 = cmul(w1, w1);
    const float2 w3 = cmul(w2, w1);
    const float2 w4 = cmul(w2, w2);
    const float2 w5 = cmul(w4, w1);
    const float2 w6 = cmul(w4, w2);
    const float2 w7 = cmul(w4, w3);
    v[1] = cmul(v[1], w1); v[2] = cmul(v[2], w2); v[3] = cmul(v[3], w3);
    v[4] = cmul(v[4], w4); v[5] = cmul(v[5], w5); v[6] = cmul(v[6], w6);
    v[7] = cmul(v[7], w7);
}

// XCD pair swizzle: hw blocks b and b+8 share an XCD (%8 round-robin); map them
// to consecutive work ids so h0-adjacent 64B zt segments meet in one L2.
__device__ __forceinline__ int xcd_pair_swizzle(int b) {
    return (b & ~15) | ((b & 7) << 1) | ((b >> 3) & 1);
}

// ---------------- kA: pad+pack + 512-pt row FFT, transposed store (natural freq).
__global__ __launch_bounds__(512, 4) void kA(const float* __restrict__ u,
                                             const float* __restrict__ kk,
                                             float2* __restrict__ zt,
                                             int img_base) {
    __shared__ float2 lds[8][LROW];
    const int wk   = xcd_pair_swizzle(blockIdx.x);
    const int imgl = wk >> 5;
    const int h0   = (wk & 31) << 3;
    const int rr   = threadIdx.x >> 6;
    const int t    = threadIdx.x & 63;
    const int h    = h0 + rr;
    const int img  = img_base + imgl;

    float2 X[8];
    {
        const size_t rowoff = ((size_t)img * H_IN + h) * W_IN;
        #pragma unroll
        for (int r = 0; r < 8; ++r) {
            const int w = t + (r << 6);
            float2 v = make_float2(0.f, 0.f);
            if (h < H_IN && w < W_IN) v = make_float2(u[rowoff + w], kk[rowoff + w]);
            X[r] = v;
        }
    }
    // phase 1: DFT8 over stride-64, twiddle W_512^{t q}
    dft8(X);
    tw8(X, -6.2831853071795864f * (float)t / 512.0f);
    #pragma unroll
    for (int q = 0; q < 8; ++q) lds[rr][(q << 6) + (t ^ (q << 3))] = X[q];
    WBAR();

    // phase 2: 8 sub-FFTs of 64; thread -> (q, j1)
    const int q  = t >> 3;
    const int j1 = t & 7;
    float2 Y[8];
    #pragma unroll
    for (int j2 = 0; j2 < 8; ++j2)
        Y[j2] = lds[rr][(q << 6) + ((j1 + (j2 << 3)) ^ (q << 3))];
    dft8(Y);
    tw8(Y, -6.2831853071795864f * (float)j1 / 64.0f);
    WBAR();
    #pragma unroll
    for (int q2 = 0; q2 < 8; ++q2)
        lds[rr][((j1 << 6) + (q2 << 3) + q) ^ ((j1 & 1) << 3)] = Y[q2];
    WBAR();

    // phase 3: DFT8 over j1; freq = 64*q3 + 8*q2 + q
    const int q2 = t & 7;
    float2 Z[8];
    #pragma unroll
    for (int j = 0; j < 8; ++j)
        Z[j] = lds[rr][((j << 6) + (q2 << 3) + q) ^ ((j & 1) << 3)];
    dft8(Z);
    WBAR();
    #pragma unroll
    for (int q3 = 0; q3 < 8; ++q3)
        lds[rr][((q3 << 6) + (q2 << 3) + q) ^ ((q3 & 1) << 3)] = Z[q3];
    __syncthreads();   // cross-wave: final gather reads all 8 rows

    // transposed store: zt[(imgl*512 + w)*256 + h], float4 (two h per lane)
    for (int idx = threadIdx.x; idx < 8 * 256; idx += 512) {
        const int w   = idx >> 2;
        const int hh2 = (idx & 3) << 1;
        const int wz  = w ^ (((w >> 6) & 1) << 3);
        const float2 a = lds[hh2][wz];
        const float2 b = lds[hh2 + 1][wz];
        reinterpret_cast<float4*>(zt)[((size_t)imgl * 512 + w) * 128 + ((h0 + hh2) >> 1)] =
            make_float4(a.x, a.y, b.x, b.y);
    }
}

// ---------------- kB: 256-pt column FFT fwd + pointwise + inv (4 conj pairs/block).
// Every LDS exchange is wave-local (a wave owns its 2 columns, and the pointwise
// pair cA/cA+1 lives in the same wave) -> no real barriers at all.
__global__ __launch_bounds__(256, 6) void kB(float2* __restrict__ zt) {
    __shared__ float2 spec[8][CSTR];
    const int imgl = blockIdx.x / 65;
    const int bq   = blockIdx.x - imgl * 65;
    const int c    = threadIdx.x >> 5;
    const int t    = threadIdx.x & 31;
    const int pi   = c >> 1, side = c & 1;
    const int g    = (bq << 2) + pi;
    const bool valid = (g <= 256);
    const bool selfp = (g == 0) || (g == 256);
    const int w    = side ? ((512 - g) & 511) : g;
    const size_t colbase = ((size_t)imgl * 512 + w) * 256;

    float2 X[8];
    #pragma unroll
    for (int r = 0; r < 8; ++r) X[r] = zt[colbase + t + (r << 5)];

    const int q  = t >> 2;
    const int j1 = t & 3;
    const int rrq = t & 3;           // q2 low bits for phase 3

    // ======== forward 256-pt ========
    dft8(X);
    tw8(X, -6.2831853071795864f * (float)t / 256.0f);
    #pragma unroll
    for (int qq = 0; qq < 8; ++qq) spec[c][(qq << 5) + (t ^ ((qq & 3) << 3))] = X[qq];
    WBAR();

    float2 Y[8];
    #pragma unroll
    for (int j2 = 0; j2 < 8; ++j2)
        Y[j2] = spec[c][(q << 5) + ((j1 + (j2 << 2)) ^ ((q & 3) << 3))];
    dft8(Y);
    tw8(Y, -6.2831853071795864f * (float)j1 / 32.0f);
    WBAR();
    #pragma unroll
    for (int q2 = 0; q2 < 8; ++q2) spec[c][(j1 << 6) + (q2 << 3) + q] = Y[q2];
    WBAR();

    float2 Za[4], Zb[4];
    #pragma unroll
    for (int j = 0; j < 4; ++j) Za[j] = spec[c][(j << 6) + (rrq << 3) + q];
    #pragma unroll
    for (int j = 0; j < 4; ++j) Zb[j] = spec[c][(j << 6) + ((rrq + 4) << 3) + q];
    dft4(Za); dft4(Zb);
    WBAR();
    #pragma unroll
    for (int k = 0; k < 4; ++k) spec[c][(k << 6) + (rrq << 3) + q] = Za[k];
    #pragma unroll
    for (int k = 0; k < 4; ++k) spec[c][(k << 6) + ((rrq + 4) << 3) + q] = Zb[k];
    WBAR();

    // ======== pointwise P = U*K (pair columns cA=2*pair, cB=cA+1) ========
    {
        const int ti = threadIdx.x & 63;
        const int cA = (threadIdx.x >> 6) << 1;
        #pragma unroll
        for (int hi = 0; hi < 4; ++hi) {
            const int h  = ti + (hi << 6);
            const int hm = (256 - h) & 255;
            const float2 Zf = spec[cA][h];
            const float2 Zm = spec[cA + 1][hm];
            const float2 U = make_float2(0.5f * (Zf.x + Zm.x),  0.5f * (Zf.y - Zm.y));
            const float2 K = make_float2(0.5f * (Zf.y + Zm.y), -0.5f * (Zf.x - Zm.x));
            const float2 P = cmul(U, K);
            spec[cA][h]      = P;
            spec[cA + 1][hm] = make_float2(P.x, -P.y);
        }
    }
    WBAR();

    // ======== inverse 256-pt via conj-trick ========
    #pragma unroll
    for (int r = 0; r < 8; ++r) {
        float2 v = spec[c][t + (r << 5)];
        X[r] = make_float2(v.x, -v.y);
    }
    WBAR();
    dft8(X);
    tw8(X, -6.2831853071795864f * (float)t / 256.0f);
    #pragma unroll
    for (int qq = 0; qq < 8; ++qq) spec[c][(qq << 5) + (t ^ ((qq & 3) << 3))] = X[qq];
    WBAR();
    #pragma unroll
    for (int j2 = 0; j2 < 8; ++j2)
        Y[j2] = spec[c][(q << 5) + ((j1 + (j2 << 2)) ^ ((q & 3) << 3))];
    dft8(Y);
    tw8(Y, -6.2831853071795864f * (float)j1 / 32.0f);
    WBAR();
    #pragma unroll
    for (int q2 = 0; q2 < 8; ++q2) spec[c][(j1 << 6) + (q2 << 3) + q] = Y[q2];
    WBAR();
    #pragma unroll
    for (int j = 0; j < 4; ++j) Za[j] = spec[c][(j << 6) + (rrq << 3) + q];
    #pragma unroll
    for (int j = 0; j < 4; ++j) Zb[j] = spec[c][(j << 6) + ((rrq + 4) << 3) + q];
    dft4(Za); dft4(Zb);
    WBAR();
    #pragma unroll
    for (int k = 0; k < 4; ++k)
        spec[c][(k << 6) + (rrq << 3) + q] = make_float2(Za[k].x, -Za[k].y);
    #pragma unroll
    for (int k = 0; k < 4; ++k)
        spec[c][(k << 6) + ((rrq + 4) << 3) + q] = make_float2(Zb[k].x, -Zb[k].y);
    WBAR();

    // write back (skip duplicate of self-paired column and masked g>256)
    if (valid && !(side && selfp)) {
        #pragma unroll
        for (int r = 0; r < 8; ++r) {
            const int h = t + (r << 5);
            zt[colbase + h] = spec[c][h];
        }
    }
}

// ---------------- kC: 512-pt inverse row FFT (conj-trick) + scale + crop.
__global__ __launch_bounds__(512, 4) void kC(const float2* __restrict__ zt,
                                             float* __restrict__ y,
                                             int img_base) {
    __shared__ float2 lds[8][LROW];
    const int wk   = xcd_pair_swizzle(blockIdx.x);
    const int imgl = wk >> 5;
    const int h0   = (wk & 31) << 3;
    const int rr   = threadIdx.x >> 6;
    const int t    = threadIdx.x & 63;
    const int img  = img_base + imgl;

    // load transposed chunk, float4 (two h per lane), natural freq w
    for (int idx = threadIdx.x; idx < 8 * 256; idx += 512) {
        const int w   = idx >> 2;
        const int hh2 = (idx & 3) << 1;
        const float4 v = reinterpret_cast<const float4*>(zt)
            [((size_t)imgl * 512 + w) * 128 + ((h0 + hh2) >> 1)];
        lds[hh2][w]     = make_float2(v.x, v.y);
        lds[hh2 + 1][w] = make_float2(v.z, v.w);
    }
    __syncthreads();   // cross-wave: scatter wrote rows from all waves

    float2 X[8];
    #pragma unroll
    for (int r = 0; r < 8; ++r) {
        float2 v = lds[rr][t + (r << 6)];
        X[r] = make_float2(v.x, -v.y);      // conj for inverse
    }
    WBAR();

    dft8(X);
    tw8(X, -6.2831853071795864f * (float)t / 512.0f);
    #pragma unroll
    for (int q = 0; q < 8; ++q) lds[rr][(q << 6) + (t ^ (q << 3))] = X[q];
    WBAR();

    const int q  = t >> 3;
    const int j1 = t & 7;
    float2 Y[8];
    #pragma unroll
    for (int j2 = 0; j2 < 8; ++j2)
        Y[j2] = lds[rr][(q << 6) + ((j1 + (j2 << 3)) ^ (q << 3))];
    dft8(Y);
    tw8(Y, -6.2831853071795864f * (float)j1 / 64.0f);
    WBAR();
    #pragma unroll
    for (int q2 = 0; q2 < 8; ++q2)
        lds[rr][((j1 << 6) + (q2 << 3) + q) ^ ((j1 & 1) << 3)] = Y[q2];
    WBAR();

    const int q2 = t & 7;
    float2 Z[8];
    #pragma unroll
    for (int j = 0; j < 8; ++j)
        Z[j] = lds[rr][((j << 6) + (q2 << 3) + q) ^ ((j & 1) << 3)];
    dft8(Z);
    WBAR();
    #pragma unroll
    for (int q3 = 0; q3 < 8; ++q3)
        lds[rr][((q3 << 6) + (q2 << 3) + q) ^ ((q3 & 1) << 3)] = Z[q3];
    __syncthreads();   // cross-wave: final gather reads all 8 rows

    const float scale = 2.1073424255447017e-08f;   // N^{-1.5}, N=131072
    for (int idx = threadIdx.x; idx < 8 * 512; idx += 512) {
        const int w  = idx & 511;
        const int hh = idx >> 9;
        const int h  = h0 + hh;
        if (h < H_IN && w < W_IN)
            y[((size_t)img * H_IN + h) * W_IN + w] =
                lds[hh][w ^ (((w >> 6) & 1) << 3)].x * scale;
    }
}

extern "C" void kernel_launch(void* const* d_in, const int* in_sizes, int n_in,
                              void* d_out, int out_size, void* d_ws, size_t ws_size,
                              hipStream_t stream) {
    const float* u = (const float*)d_in[0];
    const float* k = (const float*)d_in[1];
    float* y = (float*)d_out;
    float2* zt = (float2*)d_ws;

    const size_t per_img = (size_t)512 * 256 * sizeof(float2);   // 1 MiB
    int chunk = (int)(ws_size / per_img);
    if (chunk > NIMG) chunk = NIMG;
    if (chunk < 1) chunk = 1;

    for (int base = 0; base < NIMG; base += chunk) {
        const int nimg = (NIMG - base < chunk) ? (NIMG - base) : chunk;
        kA<<<dim3(nimg * 32), dim3(512), 0, stream>>>(u, k, zt, base);
        kB<<<dim3(nimg * 65), dim3(256), 0, stream>>>(zt);
        kC<<<dim3(nimg * 32), dim3(512), 0, stream>>>(zt, y, base);
    }
}

// Round 3
// 523.391 us; speedup vs baseline: 1.0772x; 1.0586x over previous
//
#include <hip/hip_runtime.h>
#include <math.h>

// FFT-based 2D circular convolution, B=4,C=64,H=251,W=509 -> pad 256x512.
// z = u + i*k packing; register radix-8 FFTs (8 pts/thread, 2 LDS exchanges);
// all inverse transforms via conj-trick on the forward machinery.
// zt layout: [imgl][w (natural freq)][h] -- columns contiguous (2 KB).
//
// R3 changes vs R2 (554 us):
//  - Hermitian halving: product spectrum is Hermitian -> after kB's inverse
//    column FFT, Q(h,512-w) = conj(Q(h,w)). kB writes only w=0..256; kC loads
//    w=0..256 and conj-mirrors the upper columns in LDS. -256 MB HBM traffic.
//  - REVERT XCD pair swizzle (R2 showed +12% kA write amplification vs exact
//    256 MiB in R0 with identity mapping -> pairing assumption was wrong).
//  - LROW 516 -> 518: row stride = 12 banks (mod 32) makes the 8-row column
//    gather in kA/kC exactly conflict-free (was 2-way). Phase exchanges are
//    row-local, unaffected.

#define H_IN 251
#define W_IN 509
#define NIMG 256
#define LROW 518        // 512 + 6 pad: stride 1036 dwords = 12 mod 32 (gather conflict-free)
#define CSTR 264        // 256 + 8 pad (kB column stride)

#define WBAR() __builtin_amdgcn_wave_barrier()

__device__ __forceinline__ float2 cadd(float2 a, float2 b){ return make_float2(a.x+b.x, a.y+b.y); }
__device__ __forceinline__ float2 csub(float2 a, float2 b){ return make_float2(a.x-b.x, a.y-b.y); }
__device__ __forceinline__ float2 cmul(float2 a, float2 b){ return make_float2(a.x*b.x-a.y*b.y, a.x*b.y+a.y*b.x); }
__device__ __forceinline__ float2 mnegi(float2 a){ return make_float2(a.y, -a.x); }   // a * (-i)

// 8-pt DFT, natural in -> natural out (DIF + in-register unscramble).
__device__ __forceinline__ void dft8(float2 x[8]) {
    const float s = 0.70710678118654752f;
    float2 y0=cadd(x[0],x[4]), y4=csub(x[0],x[4]);
    float2 y1=cadd(x[1],x[5]), y5=csub(x[1],x[5]);
    float2 y2=cadd(x[2],x[6]), y6=csub(x[2],x[6]);
    float2 y3=cadd(x[3],x[7]), y7=csub(x[3],x[7]);
    y5 = cmul(y5, make_float2(s, -s));
    y6 = mnegi(y6);
    y7 = cmul(y7, make_float2(-s, -s));
    float2 z0=cadd(y0,y2), z2=csub(y0,y2);
    float2 z1=cadd(y1,y3), z3=mnegi(csub(y1,y3));
    float2 z4=cadd(y4,y6), z6=csub(y4,y6);
    float2 z5=cadd(y5,y7), z7=mnegi(csub(y5,y7));
    float2 p0=cadd(z0,z1), p1=csub(z0,z1);
    float2 p2=cadd(z2,z3), p3=csub(z2,z3);
    float2 p4=cadd(z4,z5), p5=csub(z4,z5);
    float2 p6=cadd(z6,z7), p7=csub(z6,z7);
    x[0]=p0; x[1]=p4; x[2]=p2; x[3]=p6; x[4]=p1; x[5]=p5; x[6]=p3; x[7]=p7;
}

// 4-pt DFT, natural in -> natural out.
__device__ __forceinline__ void dft4(float2 x[4]) {
    float2 a=cadd(x[0],x[2]), c=csub(x[0],x[2]);
    float2 b=cadd(x[1],x[3]), d=mnegi(csub(x[1],x[3]));
    float2 p0=cadd(a,b), p1=csub(a,b);
    float2 p2=cadd(c,d), p3=csub(c,d);
    x[0]=p0; x[1]=p2; x[2]=p1; x[3]=p3;
}

// v[q] *= e^{i*ang1*q}, q=1..7 : one sincos + power recurrence (6 cmul).
__device__ __forceinline__ void tw8(float2 v[8], float ang1) {
    float sn, cs; __sincosf(ang1, &sn, &cs);
    const float2 w1 = make_float2(cs, sn);
    const float2 w2 = cmul(w1, w1);
    const float2 w3 = cmul(w2, w1);
    const float2 w4 = cmul(w2, w2);
    const float2 w5 = cmul(w4, w1);
    const float2 w6 = cmul(w4, w2);
    const float2 w7 = cmul(w4, w3);
    v[1] = cmul(v[1], w1); v[2] = cmul(v[2], w2); v[3] = cmul(v[3], w3);
    v[4] = cmul(v[4], w4); v[5] = cmul(v[5], w5); v[6] = cmul(v[6], w6);
    v[7] = cmul(v[7], w7);
}

// ---------------- kA: pad+pack + 512-pt row FFT, transposed store (natural freq).
__global__ __launch_bounds__(512, 4) void kA(const float* __restrict__ u,
                                             const float* __restrict__ kk,
                                             float2* __restrict__ zt,
                                             int img_base) {
    __shared__ float2 lds[8][LROW];
    const int imgl = blockIdx.x >> 5;
    const int h0   = (blockIdx.x & 31) << 3;
    const int rr   = threadIdx.x >> 6;
    const int t    = threadIdx.x & 63;
    const int h    = h0 + rr;
    const int img  = img_base + imgl;

    float2 X[8];
    {
        const size_t rowoff = ((size_t)img * H_IN + h) * W_IN;
        #pragma unroll
        for (int r = 0; r < 8; ++r) {
            const int w = t + (r << 6);
            float2 v = make_float2(0.f, 0.f);
            if (h < H_IN && w < W_IN) v = make_float2(u[rowoff + w], kk[rowoff + w]);
            X[r] = v;
        }
    }
    // phase 1: DFT8 over stride-64, twiddle W_512^{t q}
    dft8(X);
    tw8(X, -6.2831853071795864f * (float)t / 512.0f);
    #pragma unroll
    for (int q = 0; q < 8; ++q) lds[rr][(q << 6) + (t ^ (q << 3))] = X[q];
    WBAR();

    // phase 2: 8 sub-FFTs of 64; thread -> (q, j1)
    const int q  = t >> 3;
    const int j1 = t & 7;
    float2 Y[8];
    #pragma unroll
    for (int j2 = 0; j2 < 8; ++j2)
        Y[j2] = lds[rr][(q << 6) + ((j1 + (j2 << 3)) ^ (q << 3))];
    dft8(Y);
    tw8(Y, -6.2831853071795864f * (float)j1 / 64.0f);
    WBAR();
    #pragma unroll
    for (int q2 = 0; q2 < 8; ++q2)
        lds[rr][((j1 << 6) + (q2 << 3) + q) ^ ((j1 & 1) << 3)] = Y[q2];
    WBAR();

    // phase 3: DFT8 over j1; freq = 64*q3 + 8*q2 + q
    const int q2 = t & 7;
    float2 Z[8];
    #pragma unroll
    for (int j = 0; j < 8; ++j)
        Z[j] = lds[rr][((j << 6) + (q2 << 3) + q) ^ ((j & 1) << 3)];
    dft8(Z);
    WBAR();
    #pragma unroll
    for (int q3 = 0; q3 < 8; ++q3)
        lds[rr][((q3 << 6) + (q2 << 3) + q) ^ ((q3 & 1) << 3)] = Z[q3];
    __syncthreads();   // cross-wave: final gather reads all 8 rows

    // transposed store: zt[(imgl*512 + w)*256 + h], float4 (two h per lane)
    for (int idx = threadIdx.x; idx < 8 * 256; idx += 512) {
        const int w   = idx >> 2;
        const int hh2 = (idx & 3) << 1;
        const int wz  = w ^ (((w >> 6) & 1) << 3);
        const float2 a = lds[hh2][wz];
        const float2 b = lds[hh2 + 1][wz];
        reinterpret_cast<float4*>(zt)[((size_t)imgl * 512 + w) * 128 + ((h0 + hh2) >> 1)] =
            make_float4(a.x, a.y, b.x, b.y);
    }
}

// ---------------- kB: 256-pt column FFT fwd + pointwise + inv (4 conj pairs/block).
// Every LDS exchange is wave-local (a wave owns its 2 columns, and the pointwise
// pair cA/cA+1 lives in the same wave) -> no real barriers at all.
// Hermitian output: only columns w = 0..256 are written back.
__global__ __launch_bounds__(256, 6) void kB(float2* __restrict__ zt) {
    __shared__ float2 spec[8][CSTR];
    const int imgl = blockIdx.x / 65;
    const int bq   = blockIdx.x - imgl * 65;
    const int c    = threadIdx.x >> 5;
    const int t    = threadIdx.x & 31;
    const int pi   = c >> 1, side = c & 1;
    const int g    = (bq << 2) + pi;
    const bool valid = (g <= 256);
    const int w    = side ? ((512 - g) & 511) : g;
    const size_t colbase = ((size_t)imgl * 512 + w) * 256;

    float2 X[8];
    #pragma unroll
    for (int r = 0; r < 8; ++r) X[r] = zt[colbase + t + (r << 5)];

    const int q  = t >> 2;
    const int j1 = t & 3;
    const int rrq = t & 3;           // q2 low bits for phase 3

    // ======== forward 256-pt ========
    dft8(X);
    tw8(X, -6.2831853071795864f * (float)t / 256.0f);
    #pragma unroll
    for (int qq = 0; qq < 8; ++qq) spec[c][(qq << 5) + (t ^ ((qq & 3) << 3))] = X[qq];
    WBAR();

    float2 Y[8];
    #pragma unroll
    for (int j2 = 0; j2 < 8; ++j2)
        Y[j2] = spec[c][(q << 5) + ((j1 + (j2 << 2)) ^ ((q & 3) << 3))];
    dft8(Y);
    tw8(Y, -6.2831853071795864f * (float)j1 / 32.0f);
    WBAR();
    #pragma unroll
    for (int q2 = 0; q2 < 8; ++q2) spec[c][(j1 << 6) + (q2 << 3) + q] = Y[q2];
    WBAR();

    float2 Za[4], Zb[4];
    #pragma unroll
    for (int j = 0; j < 4; ++j) Za[j] = spec[c][(j << 6) + (rrq << 3) + q];
    #pragma unroll
    for (int j = 0; j < 4; ++j) Zb[j] = spec[c][(j << 6) + ((rrq + 4) << 3) + q];
    dft4(Za); dft4(Zb);
    WBAR();
    #pragma unroll
    for (int k = 0; k < 4; ++k) spec[c][(k << 6) + (rrq << 3) + q] = Za[k];
    #pragma unroll
    for (int k = 0; k < 4; ++k) spec[c][(k << 6) + ((rrq + 4) << 3) + q] = Zb[k];
    WBAR();

    // ======== pointwise P = U*K (pair columns cA=2*pair, cB=cA+1) ========
    {
        const int ti = threadIdx.x & 63;
        const int cA = (threadIdx.x >> 6) << 1;
        #pragma unroll
        for (int hi = 0; hi < 4; ++hi) {
            const int h  = ti + (hi << 6);
            const int hm = (256 - h) & 255;
            const float2 Zf = spec[cA][h];
            const float2 Zm = spec[cA + 1][hm];
            const float2 U = make_float2(0.5f * (Zf.x + Zm.x),  0.5f * (Zf.y - Zm.y));
            const float2 K = make_float2(0.5f * (Zf.y + Zm.y), -0.5f * (Zf.x - Zm.x));
            const float2 P = cmul(U, K);
            spec[cA][h]      = P;
            spec[cA + 1][hm] = make_float2(P.x, -P.y);
        }
    }
    WBAR();

    // ======== inverse 256-pt via conj-trick ========
    #pragma unroll
    for (int r = 0; r < 8; ++r) {
        float2 v = spec[c][t + (r << 5)];
        X[r] = make_float2(v.x, -v.y);
    }
    WBAR();
    dft8(X);
    tw8(X, -6.2831853071795864f * (float)t / 256.0f);
    #pragma unroll
    for (int qq = 0; qq < 8; ++qq) spec[c][(qq << 5) + (t ^ ((qq & 3) << 3))] = X[qq];
    WBAR();
    #pragma unroll
    for (int j2 = 0; j2 < 8; ++j2)
        Y[j2] = spec[c][(q << 5) + ((j1 + (j2 << 2)) ^ ((q & 3) << 3))];
    dft8(Y);
    tw8(Y, -6.2831853071795864f * (float)j1 / 32.0f);
    WBAR();
    #pragma unroll
    for (int q2 = 0; q2 < 8; ++q2) spec[c][(j1 << 6) + (q2 << 3) + q] = Y[q2];
    WBAR();
    #pragma unroll
    for (int j = 0; j < 4; ++j) Za[j] = spec[c][(j << 6) + (rrq << 3) + q];
    #pragma unroll
    for (int j = 0; j < 4; ++j) Zb[j] = spec[c][(j << 6) + ((rrq + 4) << 3) + q];
    dft4(Za); dft4(Zb);
    WBAR();
    #pragma unroll
    for (int k = 0; k < 4; ++k)
        spec[c][(k << 6) + (rrq << 3) + q] = make_float2(Za[k].x, -Za[k].y);
    #pragma unroll
    for (int k = 0; k < 4; ++k)
        spec[c][(k << 6) + ((rrq + 4) << 3) + q] = make_float2(Zb[k].x, -Zb[k].y);
    WBAR();

    // write back only the lower half-spectrum (w = g = 0..256); upper columns
    // are conj-redundant and reconstructed in kC.
    if (valid && !side) {
        #pragma unroll
        for (int r = 0; r < 8; ++r) {
            const int h = t + (r << 5);
            zt[colbase + h] = spec[c][h];
        }
    }
}

// ---------------- kC: 512-pt inverse row FFT (conj-trick) + scale + crop.
// Loads only w = 0..256; upper columns reconstructed via Q(h,512-w)=conj(Q(h,w)).
__global__ __launch_bounds__(512, 4) void kC(const float2* __restrict__ zt,
                                             float* __restrict__ y,
                                             int img_base) {
    __shared__ float2 lds[8][LROW];
    const int imgl = blockIdx.x >> 5;
    const int h0   = (blockIdx.x & 31) << 3;
    const int rr   = threadIdx.x >> 6;
    const int t    = threadIdx.x & 63;
    const int img  = img_base + imgl;

    // load transposed chunk, float4 (two h per lane), w = 0..256 only
    for (int idx = threadIdx.x; idx < 257 * 4; idx += 512) {
        const int w   = idx >> 2;
        const int hh2 = (idx & 3) << 1;
        const float4 v = reinterpret_cast<const float4*>(zt)
            [((size_t)imgl * 512 + w) * 128 + ((h0 + hh2) >> 1)];
        lds[hh2][w]     = make_float2(v.x, v.y);
        lds[hh2 + 1][w] = make_float2(v.z, v.w);
    }
    __syncthreads();

    // conj-mirror upper columns: w' = 257..511
    for (int idx = threadIdx.x; idx < 255 * 8; idx += 512) {
        const int wp = 257 + (idx >> 3);
        const int hh = idx & 7;
        const float2 v = lds[hh][512 - wp];
        lds[hh][wp] = make_float2(v.x, -v.y);
    }
    __syncthreads();   // cross-wave: mirror + scatter wrote rows from all waves

    float2 X[8];
    #pragma unroll
    for (int r = 0; r < 8; ++r) {
        float2 v = lds[rr][t + (r << 6)];
        X[r] = make_float2(v.x, -v.y);      // conj for inverse
    }
    WBAR();

    dft8(X);
    tw8(X, -6.2831853071795864f * (float)t / 512.0f);
    #pragma unroll
    for (int q = 0; q < 8; ++q) lds[rr][(q << 6) + (t ^ (q << 3))] = X[q];
    WBAR();

    const int q  = t >> 3;
    const int j1 = t & 7;
    float2 Y[8];
    #pragma unroll
    for (int j2 = 0; j2 < 8; ++j2)
        Y[j2] = lds[rr][(q << 6) + ((j1 + (j2 << 3)) ^ (q << 3))];
    dft8(Y);
    tw8(Y, -6.2831853071795864f * (float)j1 / 64.0f);
    WBAR();
    #pragma unroll
    for (int q2 = 0; q2 < 8; ++q2)
        lds[rr][((j1 << 6) + (q2 << 3) + q) ^ ((j1 & 1) << 3)] = Y[q2];
    WBAR();

    const int q2 = t & 7;
    float2 Z[8];
    #pragma unroll
    for (int j = 0; j < 8; ++j)
        Z[j] = lds[rr][((j << 6) + (q2 << 3) + q) ^ ((j & 1) << 3)];
    dft8(Z);
    WBAR();
    #pragma unroll
    for (int q3 = 0; q3 < 8; ++q3)
        lds[rr][((q3 << 6) + (q2 << 3) + q) ^ ((q3 & 1) << 3)] = Z[q3];
    __syncthreads();   // cross-wave: final gather reads all 8 rows

    const float scale = 2.1073424255447017e-08f;   // N^{-1.5}, N=131072
    for (int idx = threadIdx.x; idx < 8 * 512; idx += 512) {
        const int w  = idx & 511;
        const int hh = idx >> 9;
        const int h  = h0 + hh;
        if (h < H_IN && w < W_IN)
            y[((size_t)img * H_IN + h) * W_IN + w] =
                lds[hh][w ^ (((w >> 6) & 1) << 3)].x * scale;
    }
}

extern "C" void kernel_launch(void* const* d_in, const int* in_sizes, int n_in,
                              void* d_out, int out_size, void* d_ws, size_t ws_size,
                              hipStream_t stream) {
    const float* u = (const float*)d_in[0];
    const float* k = (const float*)d_in[1];
    float* y = (float*)d_out;
    float2* zt = (float2*)d_ws;

    const size_t per_img = (size_t)512 * 256 * sizeof(float2);   // 1 MiB
    int chunk = (int)(ws_size / per_img);
    if (chunk > NIMG) chunk = NIMG;
    if (chunk < 1) chunk = 1;

    for (int base = 0; base < NIMG; base += chunk) {
        const int nimg = (NIMG - base < chunk) ? (NIMG - base) : chunk;
        kA<<<dim3(nimg * 32), dim3(512), 0, stream>>>(u, k, zt, base);
        kB<<<dim3(nimg * 65), dim3(256), 0, stream>>>(zt);
        kC<<<dim3(nimg * 32), dim3(512), 0, stream>>>(zt, y, base);
    }
}

// Round 4
// 495.148 us; speedup vs baseline: 1.1386x; 1.0570x over previous
//
#include <hip/hip_runtime.h>
#include <math.h>

// FFT-based 2D circular convolution, B=4,C=64,H=251,W=509 -> pad 256x512.
// z = u + i*k packing; register radix-8 FFTs (8 pts/thread, 2 LDS exchanges);
// all inverse transforms via conj-trick on the forward machinery.
//
// R4 changes vs R3 (523 us):
//  - zt layout re-tiled: [imgl][h-block(32)][w(512)][h-in-block(8)]
//      zidx(imgl,w,h) = imgl*131072 + (h>>3)*4096 + w*8 + (h&7)
//    kA's transposed store is now a CONTIGUOUS 32KB block write; kC's load a
//    contiguous 32KB block read. kB reads/writes 64B segments at 4KB stride,
//    but adjacent w columns (same kB block) complete each 128B line.
//  - LROW 518 -> 516 revert (R3 measured: conflicts 1.887e7 -> 1.992e7, dur
//    150 -> 157 with 518; the 518 "conflict-free" theory was wrong).
//  - Hermitian halving kept: kB writes only w=0..256; kC conj-mirrors in LDS.

#define H_IN 251
#define W_IN 509
#define NIMG 256
#define LROW 516        // 512 + 4 pad (transpose staging anti-conflict)
#define CSTR 264        // 256 + 8 pad (kB column stride)

#define WBAR() __builtin_amdgcn_wave_barrier()

__device__ __forceinline__ float2 cadd(float2 a, float2 b){ return make_float2(a.x+b.x, a.y+b.y); }
__device__ __forceinline__ float2 csub(float2 a, float2 b){ return make_float2(a.x-b.x, a.y-b.y); }
__device__ __forceinline__ float2 cmul(float2 a, float2 b){ return make_float2(a.x*b.x-a.y*b.y, a.x*b.y+a.y*b.x); }
__device__ __forceinline__ float2 mnegi(float2 a){ return make_float2(a.y, -a.x); }   // a * (-i)

// 8-pt DFT, natural in -> natural out (DIF + in-register unscramble).
__device__ __forceinline__ void dft8(float2 x[8]) {
    const float s = 0.70710678118654752f;
    float2 y0=cadd(x[0],x[4]), y4=csub(x[0],x[4]);
    float2 y1=cadd(x[1],x[5]), y5=csub(x[1],x[5]);
    float2 y2=cadd(x[2],x[6]), y6=csub(x[2],x[6]);
    float2 y3=cadd(x[3],x[7]), y7=csub(x[3],x[7]);
    y5 = cmul(y5, make_float2(s, -s));
    y6 = mnegi(y6);
    y7 = cmul(y7, make_float2(-s, -s));
    float2 z0=cadd(y0,y2), z2=csub(y0,y2);
    float2 z1=cadd(y1,y3), z3=mnegi(csub(y1,y3));
    float2 z4=cadd(y4,y6), z6=csub(y4,y6);
    float2 z5=cadd(y5,y7), z7=mnegi(csub(y5,y7));
    float2 p0=cadd(z0,z1), p1=csub(z0,z1);
    float2 p2=cadd(z2,z3), p3=csub(z2,z3);
    float2 p4=cadd(z4,z5), p5=csub(z4,z5);
    float2 p6=cadd(z6,z7), p7=csub(z6,z7);
    x[0]=p0; x[1]=p4; x[2]=p2; x[3]=p6; x[4]=p1; x[5]=p5; x[6]=p3; x[7]=p7;
}

// 4-pt DFT, natural in -> natural out.
__device__ __forceinline__ void dft4(float2 x[4]) {
    float2 a=cadd(x[0],x[2]), c=csub(x[0],x[2]);
    float2 b=cadd(x[1],x[3]), d=mnegi(csub(x[1],x[3]));
    float2 p0=cadd(a,b), p1=csub(a,b);
    float2 p2=cadd(c,d), p3=csub(c,d);
    x[0]=p0; x[1]=p2; x[2]=p1; x[3]=p3;
}

// v[q] *= e^{i*ang1*q}, q=1..7 : one sincos + power recurrence (6 cmul).
__device__ __forceinline__ void tw8(float2 v[8], float ang1) {
    float sn, cs; __sincosf(ang1, &sn, &cs);
    const float2 w1 = make_float2(cs, sn);
    const float2 w2 = cmul(w1, w1);
    const float2 w3 = cmul(w2, w1);
    const float2 w4 = cmul(w2, w2);
    const float2 w5 = cmul(w4, w1);
    const float2 w6 = cmul(w4, w2);
    const float2 w7 = cmul(w4, w3);
    v[1] = cmul(v[1], w1); v[2] = cmul(v[2], w2); v[3] = cmul(v[3], w3);
    v[4] = cmul(v[4], w4); v[5] = cmul(v[5], w5); v[6] = cmul(v[6], w6);
    v[7] = cmul(v[7], w7);
}

// ---------------- kA: pad+pack + 512-pt row FFT, tiled-transposed store.
__global__ __launch_bounds__(512, 4) void kA(const float* __restrict__ u,
                                             const float* __restrict__ kk,
                                             float2* __restrict__ zt,
                                             int img_base) {
    __shared__ float2 lds[8][LROW];
    const int imgl = blockIdx.x >> 5;
    const int h0b  = blockIdx.x & 31;
    const int h0   = h0b << 3;
    const int rr   = threadIdx.x >> 6;
    const int t    = threadIdx.x & 63;
    const int h    = h0 + rr;
    const int img  = img_base + imgl;

    float2 X[8];
    {
        const size_t rowoff = ((size_t)img * H_IN + h) * W_IN;
        #pragma unroll
        for (int r = 0; r < 8; ++r) {
            const int w = t + (r << 6);
            float2 v = make_float2(0.f, 0.f);
            if (h < H_IN && w < W_IN) v = make_float2(u[rowoff + w], kk[rowoff + w]);
            X[r] = v;
        }
    }
    // phase 1: DFT8 over stride-64, twiddle W_512^{t q}
    dft8(X);
    tw8(X, -6.2831853071795864f * (float)t / 512.0f);
    #pragma unroll
    for (int q = 0; q < 8; ++q) lds[rr][(q << 6) + (t ^ (q << 3))] = X[q];
    WBAR();

    // phase 2: 8 sub-FFTs of 64; thread -> (q, j1)
    const int q  = t >> 3;
    const int j1 = t & 7;
    float2 Y[8];
    #pragma unroll
    for (int j2 = 0; j2 < 8; ++j2)
        Y[j2] = lds[rr][(q << 6) + ((j1 + (j2 << 3)) ^ (q << 3))];
    dft8(Y);
    tw8(Y, -6.2831853071795864f * (float)j1 / 64.0f);
    WBAR();
    #pragma unroll
    for (int q2 = 0; q2 < 8; ++q2)
        lds[rr][((j1 << 6) + (q2 << 3) + q) ^ ((j1 & 1) << 3)] = Y[q2];
    WBAR();

    // phase 3: DFT8 over j1; freq = 64*q3 + 8*q2 + q
    const int q2 = t & 7;
    float2 Z[8];
    #pragma unroll
    for (int j = 0; j < 8; ++j)
        Z[j] = lds[rr][((j << 6) + (q2 << 3) + q) ^ ((j & 1) << 3)];
    dft8(Z);
    WBAR();
    #pragma unroll
    for (int q3 = 0; q3 < 8; ++q3)
        lds[rr][((q3 << 6) + (q2 << 3) + q) ^ ((q3 & 1) << 3)] = Z[q3];
    __syncthreads();   // cross-wave: final gather reads all 8 rows

    // tiled store: contiguous 32KB slab (imgl, h0b): float4 idx = w*4 + hh2/2
    {
        float4* __restrict__ zt4 = reinterpret_cast<float4*>(zt);
        const size_t base4 = (((size_t)imgl << 5) + h0b) << 11;   // 2048 float4/slab
        #pragma unroll
        for (int k = 0; k < 4; ++k) {
            const int idx = (int)threadIdx.x + (k << 9);
            const int w   = idx >> 2;
            const int hh2 = (idx & 3) << 1;
            const int wz  = w ^ (((w >> 6) & 1) << 3);
            const float2 a = lds[hh2][wz];
            const float2 b = lds[hh2 + 1][wz];
            zt4[base4 + idx] = make_float4(a.x, a.y, b.x, b.y);
        }
    }
}

// ---------------- kB: 256-pt column FFT fwd + pointwise + inv (4 conj pairs/block).
// Every LDS exchange is wave-local -> no real barriers.
// Hermitian output: only columns w = 0..256 are written back.
// zt addressing: zidx = imgl*131072 + (h>>3)*4096 + w*8 + (h&7); with
// h = t + 32r: base cb = imgl<<17 | (t>>3)<<12 | w<<3 | (t&7), step r<<14.
__global__ __launch_bounds__(256, 6) void kB(float2* __restrict__ zt) {
    __shared__ float2 spec[8][CSTR];
    const int imgl = blockIdx.x / 65;
    const int bq   = blockIdx.x - imgl * 65;
    const int c    = threadIdx.x >> 5;
    const int t    = threadIdx.x & 31;
    const int pi   = c >> 1, side = c & 1;
    const int g    = (bq << 2) + pi;
    const bool valid = (g <= 256);
    const int w    = side ? ((512 - g) & 511) : g;
    const size_t cb = ((size_t)imgl << 17) + ((size_t)(t >> 3) << 12)
                    + ((size_t)w << 3) + (size_t)(t & 7);

    float2 X[8];
    #pragma unroll
    for (int r = 0; r < 8; ++r) X[r] = zt[cb + ((size_t)r << 14)];

    const int q  = t >> 2;
    const int j1 = t & 3;
    const int rrq = t & 3;           // q2 low bits for phase 3

    // ======== forward 256-pt ========
    dft8(X);
    tw8(X, -6.2831853071795864f * (float)t / 256.0f);
    #pragma unroll
    for (int qq = 0; qq < 8; ++qq) spec[c][(qq << 5) + (t ^ ((qq & 3) << 3))] = X[qq];
    WBAR();

    float2 Y[8];
    #pragma unroll
    for (int j2 = 0; j2 < 8; ++j2)
        Y[j2] = spec[c][(q << 5) + ((j1 + (j2 << 2)) ^ ((q & 3) << 3))];
    dft8(Y);
    tw8(Y, -6.2831853071795864f * (float)j1 / 32.0f);
    WBAR();
    #pragma unroll
    for (int q2 = 0; q2 < 8; ++q2) spec[c][(j1 << 6) + (q2 << 3) + q] = Y[q2];
    WBAR();

    float2 Za[4], Zb[4];
    #pragma unroll
    for (int j = 0; j < 4; ++j) Za[j] = spec[c][(j << 6) + (rrq << 3) + q];
    #pragma unroll
    for (int j = 0; j < 4; ++j) Zb[j] = spec[c][(j << 6) + ((rrq + 4) << 3) + q];
    dft4(Za); dft4(Zb);
    WBAR();
    #pragma unroll
    for (int k = 0; k < 4; ++k) spec[c][(k << 6) + (rrq << 3) + q] = Za[k];
    #pragma unroll
    for (int k = 0; k < 4; ++k) spec[c][(k << 6) + ((rrq + 4) << 3) + q] = Zb[k];
    WBAR();

    // ======== pointwise P = U*K (pair columns cA=2*pair, cB=cA+1) ========
    {
        const int ti = threadIdx.x & 63;
        const int cA = (threadIdx.x >> 6) << 1;
        #pragma unroll
        for (int hi = 0; hi < 4; ++hi) {
            const int h  = ti + (hi << 6);
            const int hm = (256 - h) & 255;
            const float2 Zf = spec[cA][h];
            const float2 Zm = spec[cA + 1][hm];
            const float2 U = make_float2(0.5f * (Zf.x + Zm.x),  0.5f * (Zf.y - Zm.y));
            const float2 K = make_float2(0.5f * (Zf.y + Zm.y), -0.5f * (Zf.x - Zm.x));
            const float2 P = cmul(U, K);
            spec[cA][h]      = P;
            spec[cA + 1][hm] = make_float2(P.x, -P.y);
        }
    }
    WBAR();

    // ======== inverse 256-pt via conj-trick ========
    #pragma unroll
    for (int r = 0; r < 8; ++r) {
        float2 v = spec[c][t + (r << 5)];
        X[r] = make_float2(v.x, -v.y);
    }
    WBAR();
    dft8(X);
    tw8(X, -6.2831853071795864f * (float)t / 256.0f);
    #pragma unroll
    for (int qq = 0; qq < 8; ++qq) spec[c][(qq << 5) + (t ^ ((qq & 3) << 3))] = X[qq];
    WBAR();
    #pragma unroll
    for (int j2 = 0; j2 < 8; ++j2)
        Y[j2] = spec[c][(q << 5) + ((j1 + (j2 << 2)) ^ ((q & 3) << 3))];
    dft8(Y);
    tw8(Y, -6.2831853071795864f * (float)j1 / 32.0f);
    WBAR();
    #pragma unroll
    for (int q2 = 0; q2 < 8; ++q2) spec[c][(j1 << 6) + (q2 << 3) + q] = Y[q2];
    WBAR();
    #pragma unroll
    for (int j = 0; j < 4; ++j) Za[j] = spec[c][(j << 6) + (rrq << 3) + q];
    #pragma unroll
    for (int j = 0; j < 4; ++j) Zb[j] = spec[c][(j << 6) + ((rrq + 4) << 3) + q];
    dft4(Za); dft4(Zb);
    WBAR();
    #pragma unroll
    for (int k = 0; k < 4; ++k)
        spec[c][(k << 6) + (rrq << 3) + q] = make_float2(Za[k].x, -Za[k].y);
    #pragma unroll
    for (int k = 0; k < 4; ++k)
        spec[c][(k << 6) + ((rrq + 4) << 3) + q] = make_float2(Zb[k].x, -Zb[k].y);
    WBAR();

    // write back only the lower half-spectrum (w = g = 0..256)
    if (valid && !side) {
        #pragma unroll
        for (int r = 0; r < 8; ++r)
            zt[cb + ((size_t)r << 14)] = spec[c][t + (r << 5)];
    }
}

// ---------------- kC: 512-pt inverse row FFT (conj-trick) + scale + crop.
// Loads only w = 0..256 (contiguous tiled slab); mirrors upper columns in LDS.
__global__ __launch_bounds__(512, 4) void kC(const float2* __restrict__ zt,
                                             float* __restrict__ y,
                                             int img_base) {
    __shared__ float2 lds[8][LROW];
    const int imgl = blockIdx.x >> 5;
    const int h0b  = blockIdx.x & 31;
    const int h0   = h0b << 3;
    const int rr   = threadIdx.x >> 6;
    const int t    = threadIdx.x & 63;
    const int img  = img_base + imgl;

    // tiled load: contiguous slab, float4 idx = w*4 + hh2/2, w = 0..256
    {
        const float4* __restrict__ zt4 = reinterpret_cast<const float4*>(zt);
        const size_t base4 = (((size_t)imgl << 5) + h0b) << 11;
        #pragma unroll
        for (int k = 0; k < 2; ++k) {
            const int idx = (int)threadIdx.x + (k << 9);
            const int w   = idx >> 2;
            const int hh2 = (idx & 3) << 1;
            const float4 v = zt4[base4 + idx];
            lds[hh2][w]     = make_float2(v.x, v.y);
            lds[hh2 + 1][w] = make_float2(v.z, v.w);
        }
        if (threadIdx.x < 4) {               // w = 256 tail
            const int idx = 1024 + (int)threadIdx.x;
            const int hh2 = (idx & 3) << 1;
            const float4 v = zt4[base4 + idx];
            lds[hh2][256]     = make_float2(v.x, v.y);
            lds[hh2 + 1][256] = make_float2(v.z, v.w);
        }
    }
    __syncthreads();

    // conj-mirror upper columns: w' = 257..511
    for (int idx = threadIdx.x; idx < 255 * 8; idx += 512) {
        const int wp = 257 + (idx >> 3);
        const int hh = idx & 7;
        const float2 v = lds[hh][512 - wp];
        lds[hh][wp] = make_float2(v.x, -v.y);
    }
    __syncthreads();   // cross-wave: mirror + scatter wrote rows from all waves

    float2 X[8];
    #pragma unroll
    for (int r = 0; r < 8; ++r) {
        float2 v = lds[rr][t + (r << 6)];
        X[r] = make_float2(v.x, -v.y);      // conj for inverse
    }
    WBAR();

    dft8(X);
    tw8(X, -6.2831853071795864f * (float)t / 512.0f);
    #pragma unroll
    for (int q = 0; q < 8; ++q) lds[rr][(q << 6) + (t ^ (q << 3))] = X[q];
    WBAR();

    const int q  = t >> 3;
    const int j1 = t & 7;
    float2 Y[8];
    #pragma unroll
    for (int j2 = 0; j2 < 8; ++j2)
        Y[j2] = lds[rr][(q << 6) + ((j1 + (j2 << 3)) ^ (q << 3))];
    dft8(Y);
    tw8(Y, -6.2831853071795864f * (float)j1 / 64.0f);
    WBAR();
    #pragma unroll
    for (int q2 = 0; q2 < 8; ++q2)
        lds[rr][((j1 << 6) + (q2 << 3) + q) ^ ((j1 & 1) << 3)] = Y[q2];
    WBAR();

    const int q2 = t & 7;
    float2 Z[8];
    #pragma unroll
    for (int j = 0; j < 8; ++j)
        Z[j] = lds[rr][((j << 6) + (q2 << 3) + q) ^ ((j & 1) << 3)];
    dft8(Z);
    WBAR();
    #pragma unroll
    for (int q3 = 0; q3 < 8; ++q3)
        lds[rr][((q3 << 6) + (q2 << 3) + q) ^ ((q3 & 1) << 3)] = Z[q3];
    __syncthreads();   // cross-wave: final gather reads all 8 rows

    const float scale = 2.1073424255447017e-08f;   // N^{-1.5}, N=131072
    for (int idx = threadIdx.x; idx < 8 * 512; idx += 512) {
        const int w  = idx & 511;
        const int hh = idx >> 9;
        const int h  = h0 + hh;
        if (h < H_IN && w < W_IN)
            y[((size_t)img * H_IN + h) * W_IN + w] =
                lds[hh][w ^ (((w >> 6) & 1) << 3)].x * scale;
    }
}

extern "C" void kernel_launch(void* const* d_in, const int* in_sizes, int n_in,
                              void* d_out, int out_size, void* d_ws, size_t ws_size,
                              hipStream_t stream) {
    const float* u = (const float*)d_in[0];
    const float* k = (const float*)d_in[1];
    float* y = (float*)d_out;
    float2* zt = (float2*)d_ws;

    const size_t per_img = (size_t)512 * 256 * sizeof(float2);   // 1 MiB
    int chunk = (int)(ws_size / per_img);
    if (chunk > NIMG) chunk = NIMG;
    if (chunk < 1) chunk = 1;

    for (int base = 0; base < NIMG; base += chunk) {
        const int nimg = (NIMG - base < chunk) ? (NIMG - base) : chunk;
        kA<<<dim3(nimg * 32), dim3(512), 0, stream>>>(u, k, zt, base);
        kB<<<dim3(nimg * 65), dim3(256), 0, stream>>>(zt);
        kC<<<dim3(nimg * 32), dim3(512), 0, stream>>>(zt, y, base);
    }
}